// Round 2
// baseline (1011.290 us; speedup 1.0000x reference)
//
#include <hip/hip_runtime.h>
#include <hip/hip_bf16.h>

typedef unsigned short u16;
typedef __attribute__((ext_vector_type(8))) short short8;
typedef __attribute__((ext_vector_type(4))) float f32x4;

#define SD   128
#define SNIN 384
#define SK   48
#define HPAD 136   // 128+8 elems -> row stride 272B (16B-aligned, bank-friendly)
#define FPAD 520   // 512+8 elems

// ws layout (bytes) — packed bf16 weights only (448 KB total)
#define OFF_W1A   0
#define OFF_W1B   32768
#define OFF_W2    131072
#define OFF_W3    163840
#define OFF_WIN   196608
#define OFF_WOUT  327680

__device__ __forceinline__ u16 f2b(float f){
  union { float f; unsigned u; } v; v.f = f;
  unsigned r = (v.u + 0x7FFFu + ((v.u >> 16) & 1u)) >> 16;   // RNE
  return (u16)r;
}
__device__ __forceinline__ short8 ldg8(const u16* p){
  return *reinterpret_cast<const short8*>(p);
}
// pack 8 consecutive fp32 -> bf16 A-fragment (two dwordx4 loads + RNE cvt)
__device__ __forceinline__ short8 cvt8(const float* p){
  float4 a = *reinterpret_cast<const float4*>(p);
  float4 b = *reinterpret_cast<const float4*>(p + 4);
  short8 r;
  r[0]=(short)f2b(a.x); r[1]=(short)f2b(a.y); r[2]=(short)f2b(a.z); r[3]=(short)f2b(a.w);
  r[4]=(short)f2b(b.x); r[5]=(short)f2b(b.y); r[6]=(short)f2b(b.z); r[7]=(short)f2b(b.w);
  return r;
}

// gelu(x)=0.5*x*(1+erf(x/sqrt2)); odd deg-7 poly of erf on [-3,3], clamped. abs err < 7e-3.
__device__ __forceinline__ float gelu_f(float x){
  float xc = fminf(3.0f, fmaxf(-3.0f, x));
  float u  = xc*xc;
  float p  = fmaf(u, fmaf(u, fmaf(u, -4.81034e-4f, 1.185750e-2f), -1.1877797e-1f), 7.9165011e-1f);
  float t  = xc*p;
  float hx = 0.5f*x;
  return fmaf(t, hx, hx);
}

// ---------------- prep: fp32 weights -> bf16 MFMA B-fragment-linear layout ----------------
// B-frag (16x16x32): lane holds B[k=(lane>>4)*8+j][n=nt*16+(lane&15)], j=0..7.
// Frag order: ((ks*NT + nt)*64 + lane)*8 elems -> 16B contiguous per lane.
__global__ __launch_bounds__(256) void prep_pack(
    const float* __restrict__ W1, const float* __restrict__ W2, const float* __restrict__ W3,
    const float* __restrict__ Win, const float* __restrict__ Wout, u16* __restrict__ ws)
{
  int t = blockIdx.x*256 + threadIdx.x;   // 28672 frag-lanes total
  const float* src; int stride, rowoff, NT; u16* dst; int local;
  if (t < 2048)       { src=W1;  stride=SD;  rowoff=0;   NT=8;  dst=ws+OFF_W1A/2;  local=t;       }
  else if (t < 8192)  { src=W1;  stride=SD;  rowoff=128; NT=8;  dst=ws+OFF_W1B/2;  local=t-2048;  }
  else if (t < 10240) { src=W2;  stride=SD;  rowoff=0;   NT=8;  dst=ws+OFF_W2/2;   local=t-8192;  }
  else if (t < 12288) { src=W3;  stride=SD;  rowoff=0;   NT=8;  dst=ws+OFF_W3/2;   local=t-10240; }
  else if (t < 20480) { src=Win; stride=512; rowoff=0;   NT=32; dst=ws+OFF_WIN/2;  local=t-12288; }
  else                { src=Wout;stride=SD;  rowoff=0;   NT=8;  dst=ws+OFF_WOUT/2; local=t-20480; }
  int lane = local & 63;
  int blk  = local >> 6;
  int nt = blk % NT, ks = blk / NT;
  int k0 = rowoff + ks*32 + (lane>>4)*8;
  int n  = nt*16 + (lane & 15);
  union { u16 a[8]; short8 v; } tmp;
  #pragma unroll
  for (int j=0;j<8;j++) tmp.a[j] = f2b(src[(size_t)(k0+j)*stride + n]);
  *reinterpret_cast<short8*>(dst + (size_t)local*8) = tmp.v;
}

// ---------------- kernel A: one wave per node; fused MLP + masked K-sum + LN1 ----------------
// u (LN1 output, fp32) written to d_out; ffn_ln then updates d_out in place (block-local rows).
__global__ __launch_bounds__(256, 2) void dec_nodes(
    const float* __restrict__ hV, const float* __restrict__ hE, const float* __restrict__ mAtt,
    const float* __restrict__ b1, const float* __restrict__ b2, const float* __restrict__ b3,
    const float* __restrict__ g1, const float* __restrict__ o1,
    const u16* __restrict__ ws, float* __restrict__ u_out)
{
  __shared__ u16 HH[4][SK*HPAD];   // per-wave scratch: holds H1, then reused for H2

  const int tid  = threadIdx.x;
  const int w    = tid >> 6;
  const int lane = tid & 63;
  const int quad = lane >> 4;
  const int l16  = lane & 15;
  const int g    = blockIdx.x*4 + w;   // this wave's node
  u16* HHw = HH[w];

  // ---- base1[n] = (hV[g] @ W1[:128])[n] + b1[n], n = nt*16+l16 (8 per lane), via broadcast-A MFMA
  float base1v[8];
  {
    f32x4 accb[8];
    #pragma unroll
    for (int nt=0;nt<8;nt++) accb[nt] = (f32x4){0.f,0.f,0.f,0.f};
    const u16* Bb = ws + OFF_W1A/2 + (size_t)lane*8;
    #pragma unroll
    for (int ks=0; ks<4; ks++){
      short8 af = cvt8(hV + (size_t)g*SD + ks*32 + quad*8);  // same 8 floats across l16 -> rows identical
      #pragma unroll
      for (int nt=0; nt<8; nt++){
        short8 bf = ldg8(Bb + ((size_t)(ks*8+nt)*64)*8);
        accb[nt] = __builtin_amdgcn_mfma_f32_16x16x32_bf16(af, bf, accb[nt], 0,0,0);
      }
    }
    #pragma unroll
    for (int nt=0;nt<8;nt++) base1v[nt] = accb[nt][0] + b1[nt*16 + l16];
  }

  // ---- G1: H1 = gelu(hE[g] (48x384) @ W1[128:] + base1)
  f32x4 acc[24];
  #pragma unroll
  for (int i=0;i<24;i++) acc[i] = (f32x4){0.f,0.f,0.f,0.f};
  {
    const float* Ab = hE + (size_t)g*(SK*SNIN) + (size_t)l16*SNIN + quad*8;
    const u16*  Bb = ws + OFF_W1B/2 + (size_t)lane*8;
    #pragma unroll
    for (int ks=0; ks<12; ks++){
      short8 af[3];
      #pragma unroll
      for (int mt=0; mt<3; mt++) af[mt] = cvt8(Ab + (size_t)mt*16*SNIN + ks*32);
      #pragma unroll
      for (int nt=0; nt<8; nt++){
        short8 bf = ldg8(Bb + ((size_t)(ks*8+nt)*64)*8);
        #pragma unroll
        for (int mt=0; mt<3; mt++)
          acc[mt*8+nt] = __builtin_amdgcn_mfma_f32_16x16x32_bf16(af[mt], bf, acc[mt*8+nt], 0,0,0);
      }
    }
    #pragma unroll
    for (int mt=0; mt<3; mt++)
      #pragma unroll
      for (int nt=0; nt<8; nt++)
        #pragma unroll
        for (int i=0;i<4;i++){
          int row = mt*16 + quad*4 + i;
          HHw[row*HPAD + nt*16 + l16] = f2b(gelu_f(acc[mt*8+nt][i] + base1v[nt]));
        }
  }
  __syncthreads();

  // ---- G2: H2 = gelu(H1 @ W2 + b2)  (reuse acc regs; reuse HH buffer after full read)
  #pragma unroll
  for (int i=0;i<24;i++) acc[i] = (f32x4){0.f,0.f,0.f,0.f};
  {
    const u16* Bb = ws + OFF_W2/2 + (size_t)lane*8;
    #pragma unroll
    for (int ks=0; ks<4; ks++){
      short8 af[3];
      #pragma unroll
      for (int mt=0; mt<3; mt++)
        af[mt] = *reinterpret_cast<const short8*>(&HHw[(mt*16+l16)*HPAD + ks*32 + quad*8]);
      #pragma unroll
      for (int nt=0; nt<8; nt++){
        short8 bf = ldg8(Bb + ((size_t)(ks*8+nt)*64)*8);
        #pragma unroll
        for (int mt=0; mt<3; mt++)
          acc[mt*8+nt] = __builtin_amdgcn_mfma_f32_16x16x32_bf16(af[mt], bf, acc[mt*8+nt], 0,0,0);
      }
    }
  }
  __syncthreads();   // all H1 reads done before overwrite (also compiler fence)
  {
    #pragma unroll
    for (int mt=0; mt<3; mt++)
      #pragma unroll
      for (int nt=0; nt<8; nt++){
        float bb = b2[nt*16 + l16];
        #pragma unroll
        for (int i=0;i<4;i++){
          int row = mt*16 + quad*4 + i;
          HHw[row*HPAD + nt*16 + l16] = f2b(gelu_f(acc[mt*8+nt][i] + bb));
        }
      }
  }
  __syncthreads();

  // ---- G3: M = H2 @ W3 + b3; dh[n] = sum_k mask[k]*M[k][n]
  #pragma unroll
  for (int i=0;i<24;i++) acc[i] = (f32x4){0.f,0.f,0.f,0.f};
  {
    const u16* Bb = ws + OFF_W3/2 + (size_t)lane*8;
    #pragma unroll
    for (int ks=0; ks<4; ks++){
      short8 af[3];
      #pragma unroll
      for (int mt=0; mt<3; mt++)
        af[mt] = *reinterpret_cast<const short8*>(&HHw[(mt*16+l16)*HPAD + ks*32 + quad*8]);
      #pragma unroll
      for (int nt=0; nt<8; nt++){
        short8 bf = ldg8(Bb + ((size_t)(ks*8+nt)*64)*8);
        #pragma unroll
        for (int mt=0; mt<3; mt++)
          acc[mt*8+nt] = __builtin_amdgcn_mfma_f32_16x16x32_bf16(af[mt], bf, acc[mt*8+nt], 0,0,0);
      }
    }
  }
  float p[8];
  {
    #pragma unroll
    for (int nt=0;nt<8;nt++) p[nt] = 0.f;
    #pragma unroll
    for (int mt=0; mt<3; mt++)
      #pragma unroll
      for (int i=0;i<4;i++){
        float m = mAtt[(size_t)g*SK + mt*16 + quad*4 + i];
        #pragma unroll
        for (int nt=0; nt<8; nt++){
          float bb = b3[nt*16 + l16];
          p[nt] = fmaf(m, acc[mt*8+nt][i] + bb, p[nt]);
        }
      }
    #pragma unroll
    for (int nt=0;nt<8;nt++){
      p[nt] += __shfl_down(p[nt], 32, 64);
      p[nt] += __shfl_down(p[nt], 16, 64);
      p[nt]  = __shfl(p[nt], l16, 64);     // broadcast quad0's reduced value to all quads
    }
  }

  // ---- LN1: u = LN(hV + dh/30)*g1 + o1   (each col counted 4x across quads in the wave sum)
  {
    float x[8];
    float s = 0.f, q = 0.f;
    #pragma unroll
    for (int nt=0;nt<8;nt++){
      x[nt] = hV[(size_t)g*SD + nt*16 + l16] + p[nt]*(1.0f/30.0f);
      s += x[nt]; q = fmaf(x[nt], x[nt], q);
    }
    #pragma unroll
    for (int off=1; off<64; off<<=1){ s += __shfl_xor(s, off, 64); q += __shfl_xor(q, off, 64); }
    float mu  = s * (1.0f/512.0f);          // 4x duplication: /(4*128)
    float var = q * (1.0f/512.0f) - mu*mu;
    float rs  = rsqrtf(var + 1e-5f);
    #pragma unroll
    for (int k=0;k<2;k++){
      int nt = 2*quad + k;
      float uv = (x[nt]-mu)*rs*g1[nt*16+l16] + o1[nt*16+l16];
      u_out[(size_t)g*SD + nt*16 + l16] = uv;
    }
  }
}

// ---------------- kernel B: batched FFN + residual + LN2 + mask_V (in-place on d_out) --------
__global__ __launch_bounds__(128) void ffn_ln(
    const float* __restrict__ b_in, const float* __restrict__ b_out,
    const float* __restrict__ g2, const float* __restrict__ o2, const float* __restrict__ mV,
    const u16* __restrict__ ws, float* __restrict__ uo)
{
  __shared__ u16 fS[2][16*FPAD];
  const int tid = threadIdx.x, w = tid>>6, lane = tid&63, quad = lane>>4, l16 = lane&15;
  const int m0 = blockIdx.x*32 + w*16;

  short8 afr[4];
  const float* Ap = uo + (size_t)(m0 + l16)*SD + quad*8;
  #pragma unroll
  for (int ks=0; ks<4; ks++) afr[ks] = cvt8(Ap + ks*32);

  // FFN1: f = gelu(u @ W_in + b_in), N=512 in 4 blocks of 128
  #pragma unroll
  for (int nb=0; nb<4; nb++){
    f32x4 acc[8];
    #pragma unroll
    for (int t=0;t<8;t++) acc[t] = (f32x4){0.f,0.f,0.f,0.f};
    const u16* Bp = ws + OFF_WIN/2 + ((size_t)(nb*8)*64 + lane)*8;
    #pragma unroll
    for (int ks=0; ks<4; ks++){
      #pragma unroll
      for (int t=0;t<8;t++){
        short8 bf = ldg8(Bp + ((size_t)ks*32 + t)*512);
        acc[t] = __builtin_amdgcn_mfma_f32_16x16x32_bf16(afr[ks], bf, acc[t], 0,0,0);
      }
    }
    #pragma unroll
    for (int t=0;t<8;t++){
      int coln = nb*128 + t*16 + l16;
      float bi = b_in[coln];
      #pragma unroll
      for (int i=0;i<4;i++)
        fS[w][(quad*4+i)*FPAD + coln] = f2b(gelu_f(acc[t][i] + bi));
    }
  }
  __syncthreads();   // compiler fence for LDS write->read ordering

  // FFN2: dh2 = f @ W_out + b_out
  f32x4 acc2[8];
  #pragma unroll
  for (int t=0;t<8;t++) acc2[t] = (f32x4){0.f,0.f,0.f,0.f};
  const u16* Bo = ws + OFF_WOUT/2 + (size_t)lane*8;
  #pragma unroll
  for (int ks=0; ks<16; ks++){
    const short8 af = *reinterpret_cast<const short8*>(&fS[w][l16*FPAD + ks*32 + quad*8]);
    #pragma unroll
    for (int t=0;t<8;t++){
      short8 bf = ldg8(Bo + ((size_t)ks*8 + t)*512);
      acc2[t] = __builtin_amdgcn_mfma_f32_16x16x32_bf16(af, bf, acc2[t], 0,0,0);
    }
  }

  // residual + LN2 + mask_V, write fp32 out (same rows this block read)
  float bov[8], g2v[8], o2v[8];
  #pragma unroll
  for (int t=0;t<8;t++){
    int cl = t*16 + l16;
    bov[t] = b_out[cl]; g2v[t] = g2[cl]; o2v[t] = o2[cl];
  }
  #pragma unroll
  for (int i=0;i<4;i++){
    int r = m0 + quad*4 + i;
    float xv[8];
    float s = 0.f, q = 0.f;
    #pragma unroll
    for (int t=0;t<8;t++){
      xv[t] = uo[(size_t)r*SD + t*16 + l16] + acc2[t][i] + bov[t];
      s += xv[t]; q = fmaf(xv[t], xv[t], q);
    }
    #pragma unroll
    for (int mk=1; mk<16; mk<<=1){ s += __shfl_xor(s, mk, 64); q += __shfl_xor(q, mk, 64); }
    float mu  = s * (1.0f/128.0f);
    float var = q * (1.0f/128.0f) - mu*mu;
    float rs  = rsqrtf(var + 1e-5f);
    float mv  = mV[r];
    #pragma unroll
    for (int t=0;t<8;t++)
      uo[(size_t)r*SD + t*16 + l16] = mv * ((xv[t]-mu)*rs*g2v[t] + o2v[t]);
  }
}

extern "C" void kernel_launch(void* const* d_in, const int* in_sizes, int n_in,
                              void* d_out, int out_size, void* d_ws, size_t ws_size,
                              hipStream_t stream) {
  (void)n_in; (void)out_size; (void)ws_size;
  const float* hV    = (const float*)d_in[0];
  const float* hE    = (const float*)d_in[1];
  const float* mV    = (const float*)d_in[2];
  const float* mAtt  = (const float*)d_in[3];
  const float* W1    = (const float*)d_in[4];
  const float* b1    = (const float*)d_in[5];
  const float* W2    = (const float*)d_in[6];
  const float* b2    = (const float*)d_in[7];
  const float* W3    = (const float*)d_in[8];
  const float* b3    = (const float*)d_in[9];
  const float* Win   = (const float*)d_in[10];
  const float* b_in  = (const float*)d_in[11];
  const float* Wout  = (const float*)d_in[12];
  const float* b_out = (const float*)d_in[13];
  const float* g1    = (const float*)d_in[14];
  const float* o1    = (const float*)d_in[15];
  const float* g2    = (const float*)d_in[16];
  const float* o2    = (const float*)d_in[17];
  u16*   ws   = (u16*)d_ws;
  float* outp = (float*)d_out;
  const int NG = in_sizes[0] / SD;   // 8192 nodes

  hipLaunchKernelGGL(prep_pack, dim3(112), dim3(256), 0, stream, W1, W2, W3, Win, Wout, ws);
  hipLaunchKernelGGL(dec_nodes, dim3(NG/4), dim3(256), 0, stream,
                     hV, hE, mAtt, b1, b2, b3, g1, o1, ws, outp);
  hipLaunchKernelGGL(ffn_ln, dim3(NG/32), dim3(128), 0, stream,
                     b_in, b_out, g2, o2, mV, ws, outp);
}